// Round 4
// baseline (355.669 us; speedup 1.0000x reference)
//
#include <hip/hip_runtime.h>

#define BB 4
#define CC 32
#define HH 512
#define WW 512
#define PLANE ((size_t)HH * WW)

typedef float vfloat4 __attribute__((ext_vector_type(4)));

// ---------------------------------------------------------------------------
// Fully fused deformable-conv: per thread (1 row x 4 px):
//   1) off_x/off_y = conv3x3(x, w_off[0:2]) + b_off[0:2]   (registers only)
//   2) bilinear zero-padded gather of all 32 channels at (w+off_x, h+off_y)
// No LDS, no barriers, no off buffer. Software-pipelined conv loads (2 ch).
// Grid 1024 blocks, XCD-band swizzled: each XCD owns 256 contiguous rows of
// one batch image -> conv halo rows and gather rows are L2-resident.
// ---------------------------------------------------------------------------
__global__ __launch_bounds__(256) void fused_kernel(
    const float* __restrict__ x, const float* __restrict__ w_off,
    const float* __restrict__ b_off, float* __restrict__ out) {
  const int nb = gridDim.x;                       // 1024
  const int i  = blockIdx.x;
  const int j  = (i & 7) * (nb >> 3) + (i >> 3);  // XCD band swizzle
  const int b  = j >> 8;                          // 256 row-pairs per batch
  const int h  = ((j & 255) << 1) + (threadIdx.x >> 7);
  const int w4 = (threadIdx.x & 127) << 2;        // 0..508

  const float* xb = x + (size_t)b * CC * PLANE;
  const float* xr = xb + (size_t)h * WW + w4;

  float4 acc0, acc1;
  {
    const float b0 = b_off[0], b1 = b_off[1];
    acc0.x = acc0.y = acc0.z = acc0.w = b0;
    acc1.x = acc1.y = acc1.z = acc1.w = b1;
  }

  // ---- phase 1: 3x3x32 conv for 2 output channels, software-pipelined ----
  auto load_ch = [&](int ci, float4* mm, float* el, float* er) {
    const float* base = xr + (size_t)ci * PLANE;
#pragma unroll
    for (int kr = 0; kr < 3; ++kr) {
      const int hy = h + kr - 1;
      if (hy >= 0 && hy < HH) {
        const float* p = base + (ptrdiff_t)(kr - 1) * WW;
        mm[kr] = *(const float4*)p;               // 16B aligned
        el[kr] = (w4 > 0) ? p[-1] : 0.f;
        er[kr] = (w4 < WW - 4) ? p[4] : 0.f;
      } else {
        mm[kr] = make_float4(0.f, 0.f, 0.f, 0.f);
        el[kr] = 0.f;
        er[kr] = 0.f;
      }
    }
  };
  auto fma_ch = [&](int ci, const float4* mm, const float* el, const float* er) {
    const float* wp0 = w_off + ci * 9;            // co=0, layout [co][ci][kh][kw]
    const float* wp1 = w_off + 288 + ci * 9;      // co=1
#pragma unroll
    for (int kh = 0; kh < 3; ++kh) {
      const float a0 = wp0[kh * 3 + 0], a1 = wp0[kh * 3 + 1], a2 = wp0[kh * 3 + 2];
      const float c0 = wp1[kh * 3 + 0], c1 = wp1[kh * 3 + 1], c2 = wp1[kh * 3 + 2];
      const float vl = el[kh], vr = er[kh];
      const float v0 = mm[kh].x, v1 = mm[kh].y, v2 = mm[kh].z, v3 = mm[kh].w;
      acc0.x += vl * a0 + v0 * a1 + v1 * a2;
      acc0.y += v0 * a0 + v1 * a1 + v2 * a2;
      acc0.z += v1 * a0 + v2 * a1 + v3 * a2;
      acc0.w += v2 * a0 + v3 * a1 + vr * a2;
      acc1.x += vl * c0 + v0 * c1 + v1 * c2;
      acc1.y += v0 * c0 + v1 * c1 + v2 * c2;
      acc1.z += v1 * c0 + v2 * c1 + v3 * c2;
      acc1.w += v2 * c0 + v3 * c1 + vr * c2;
    }
  };

  {
    float4 mA[3], mB[3];
    float lA[3], rA[3], lB[3], rB[3];
    load_ch(0, mA, lA, rA);
#pragma unroll 4
    for (int ci = 0; ci < CC; ci += 2) {
      load_ch(ci + 1, mB, lB, rB);     // in flight while A's FMAs run
      fma_ch(ci, mA, lA, rA);
      if (ci + 2 < CC) load_ch(ci + 2, mA, lA, rA);
      fma_ch(ci + 1, mB, lB, rB);
    }
  }

  // ---- phase 2: bilinear gather of 32 channels for this thread's 4 px ----
  int i00[4], i01[4], i10[4], i11[4];
  float w00[4], w01[4], w10[4], w11[4];
#pragma unroll
  for (int p = 0; p < 4; ++p) {
    const float ox = (p == 0) ? acc0.x : (p == 1) ? acc0.y : (p == 2) ? acc0.z : acc0.w;
    const float oy = (p == 0) ? acc1.x : (p == 1) ? acc1.y : (p == 2) ? acc1.z : acc1.w;
    const float ix = (float)(w4 + p) + ox;
    const float iy = (float)h + oy;

    const float x0f = floorf(ix);
    const float y0f = floorf(iy);
    const float wx1 = ix - x0f, wx0 = 1.f - wx1;
    const float wy1 = iy - y0f, wy0 = 1.f - wy1;

    const bool vx0 = (x0f >= 0.f) && (x0f <= (float)(WW - 1));
    const bool vx1 = (x0f + 1.f >= 0.f) && (x0f + 1.f <= (float)(WW - 1));
    const bool vy0 = (y0f >= 0.f) && (y0f <= (float)(HH - 1));
    const bool vy1 = (y0f + 1.f >= 0.f) && (y0f + 1.f <= (float)(HH - 1));

    const int xi0 = (int)fminf(fmaxf(x0f, 0.f), (float)(WW - 1));
    const int xi1 = (int)fminf(fmaxf(x0f + 1.f, 0.f), (float)(WW - 1));
    const int yi0 = (int)fminf(fmaxf(y0f, 0.f), (float)(HH - 1));
    const int yi1 = (int)fminf(fmaxf(y0f + 1.f, 0.f), (float)(HH - 1));

    w00[p] = wy0 * wx0 * ((vy0 && vx0) ? 1.f : 0.f);
    w01[p] = wy0 * wx1 * ((vy0 && vx1) ? 1.f : 0.f);
    w10[p] = wy1 * wx0 * ((vy1 && vx0) ? 1.f : 0.f);
    w11[p] = wy1 * wx1 * ((vy1 && vx1) ? 1.f : 0.f);

    i00[p] = yi0 * WW + xi0;
    i01[p] = yi0 * WW + xi1;
    i10[p] = yi1 * WW + xi0;
    i11[p] = yi1 * WW + xi1;
  }

  const float* xp = xb;
  float* ob = out + (size_t)b * CC * PLANE + (size_t)h * WW + w4;
#pragma unroll 4
  for (int c = 0; c < CC; ++c) {
    vfloat4 v;
#pragma unroll
    for (int p = 0; p < 4; ++p) {
      v[p] = w00[p] * xp[i00[p]] + w01[p] * xp[i01[p]] +
             w10[p] * xp[i10[p]] + w11[p] * xp[i11[p]];
    }
    __builtin_nontemporal_store(v, (vfloat4*)ob);
    xp += PLANE;
    ob += PLANE;
  }
}

extern "C" void kernel_launch(void* const* d_in, const int* in_sizes, int n_in,
                              void* d_out, int out_size, void* d_ws, size_t ws_size,
                              hipStream_t stream) {
  const float* x     = (const float*)d_in[0];
  const float* w_off = (const float*)d_in[1];
  const float* b_off = (const float*)d_in[2];
  float* out = (float*)d_out;

  fused_kernel<<<1024, 256, 0, stream>>>(x, w_off, b_off, out);
}